// Round 11
// baseline (345.242 us; speedup 1.0000x reference)
//
#include <hip/hip_runtime.h>
#include <hip/hip_bf16.h>
#include <stdint.h>

typedef unsigned short ushort_t;
typedef __attribute__((ext_vector_type(8))) short short8;
typedef __attribute__((ext_vector_type(4))) float floatx4;
typedef __attribute__((ext_vector_type(2))) float floatx2;

__device__ __forceinline__ unsigned short f2bf(float f){
  union { float f; unsigned int i; } v; v.f = f;
  unsigned int r = v.i + 0x7FFFu + ((v.i >> 16) & 1u);
  return (unsigned short)(r >> 16);
}
__device__ __forceinline__ unsigned int pack2(unsigned short lo, unsigned short hi){
  return ((unsigned int)hi << 16) | (unsigned int)lo;
}
// packed bf16-pair -> float2; accumulate via packed f32 add
__device__ __forceinline__ floatx2 bfpair(unsigned int v){
  union { unsigned int u; float f; } lo, hi;
  lo.u = v << 16; hi.u = v & 0xffff0000u;
  floatx2 r; r.x = lo.f; r.y = hi.f; return r;
}

// ---------------- prep kernel (1024 thr): [hist + dflag | x->bf16 | weight perm + zero rows] ----------------

__global__ __launch_bounds__(1024)
void k_prep(const unsigned int* __restrict__ w, int* __restrict__ ghist, int* __restrict__ dflag,
            int E, int N, int nbB,
            const float2* __restrict__ xin, unsigned int* __restrict__ xb, int total2, int tobfB,
            const float* __restrict__ W1a, const float* __restrict__ W1b, const float* __restrict__ W2a,
            const float* __restrict__ W2b, const float* __restrict__ W3a, const float* __restrict__ W3b,
            const float* __restrict__ Wfc, ushort_t* __restrict__ wout,
            ushort_t* __restrict__ xbz, ushort_t* __restrict__ x1z, ushort_t* __restrict__ ybz)
{
  int b = blockIdx.x, t = threadIdx.x;
  if (b < nbB){
    __shared__ int h[256];
    __shared__ unsigned int dred[16];
    if (t < 256) h[t] = 0;
    int base = b*4096 + t;
    unsigned int acc = 0;
    #pragma unroll
    for (int i=0;i<4;++i){
      int e = base + i*1024;
      if (e < E) acc |= w[2*e+1];
    }
    #pragma unroll
    for (int o=32;o>=1;o>>=1) acc |= __shfl_xor(acc, o);
    if ((t&63)==0) dred[t>>6] = acc;
    __syncthreads();
    unsigned int mm = 0;
    #pragma unroll
    for (int i=0;i<16;++i) mm |= dred[i];
    int m = mm != 0;                          // 1 => int32 words
    if (t == 0) dflag[b] = m;
    #pragma unroll
    for (int i=0;i<4;++i){
      int e = base + i*1024;
      if (e < E){
        int d = m ? (int)w[(size_t)E + e] : (int)w[2*((size_t)E + e)];
        if ((unsigned)d < (unsigned)N) atomicAdd(&h[d>>9], 1);
      }
    }
    __syncthreads();
    if (t < 256 && h[t]) atomicAdd(&ghist[t], h[t]);
  } else if (b < nbB + tobfB){
    int i = (b - nbB)*1024 + t;
    if (i < total2){
      float2 v = xin[i];
      xb[i] = pack2(f2bf(v.x), f2bf(v.y));
    }
  } else {
    int id = (b - nbB - tobfB)*1024 + t;
    if (id >= 74752){
      int id2 = id - 74752;
      if      (id2 <  64) xbz[id2]      = 0;   // xb zero row (64)
      else if (id2 < 192) x1z[id2-64]   = 0;   // x1 zero row (128)
      else if (id2 < 256) ybz[id2-192]  = 0;   // ybuf zero row (64)
      return;
    }
    const float* src; int K, M, base2, local;
    if      (id <  8192){ src=W1a; K=64;  M=128; base2=0;     local=id; }
    else if (id < 24576){ src=W1b; K=128; M=128; base2=8192;  local=id-8192; }
    else if (id < 40960){ src=W2a; K=128; M=128; base2=24576; local=id-24576; }
    else if (id < 57344){ src=W2b; K=128; M=128; base2=40960; local=id-40960; }
    else if (id < 65536){ src=W3a; K=128; M=64;  base2=57344; local=id-57344; }
    else if (id < 69632){ src=W3b; K=64;  M=64;  base2=65536; local=id-65536; }
    else if (id < 70656){ src=Wfc; K=64;  M=16;  base2=69632; local=id-69632; }
    else                { src=nullptr; K=64; M=64; base2=70656; local=id-70656; } // identity
    int k = local / M, nn = local - k*M;
    float val;
    if (src == nullptr) val = (k == nn) ? 1.0f : 0.0f;
    else if (src == Wfc) val = (nn<8) ? Wfc[k*8+nn] : 0.0f;
    else                 val = src[k*M+nn];
    int idx = (((nn>>4)*(K/32) + (k>>5))*4 + ((k>>3)&3))*128 + (nn&15)*8 + (k&7);
    wout[base2+idx] = f2bf(val);
  }
}

// ---------------- CSR build via 512-node bucket counting sort (1024-thread blocks) ----------------
// pairs packed u32: (dloc:9 | src:17) -- valid for N < 131072 (problem N = 100000).

__global__ __launch_bounds__(1024) void k_bin(const unsigned int* __restrict__ w,
                                              const int* __restrict__ ghist, const int* __restrict__ dflag,
                                              int* __restrict__ gcur,
                                              unsigned int* __restrict__ pairs,
                                              int E, int N, int NB){
  __shared__ int sv[256];
  __shared__ int h[256];
  __shared__ int cur[256];
  int t = threadIdx.x;
  int gv = 0;
  if (t < 256){ gv = ghist[t]; sv[t] = gv; }
  __syncthreads();
  for (int o=1;o<256;o<<=1){
    int xv = (t>=o && t<256)? sv[t-o] : 0;
    __syncthreads();
    if (t < 256) sv[t] += xv;
    __syncthreads();
  }
  int excl = (t < 256) ? sv[t] - gv : 0;
  if (t < 256) h[t] = 0;
  int m = dflag[blockIdx.x];
  int base = blockIdx.x*4096 + t;
  __syncthreads();
  int d[4], s[4];
  #pragma unroll
  for (int i=0;i<4;++i){
    int e = base + i*1024;
    d[i] = -1; s[i] = 0;
    if (e < E){
      if (m){ s[i] = (int)w[e];           d[i] = (int)w[(size_t)E + e]; }
      else  { s[i] = (int)w[2*(size_t)e]; d[i] = (int)w[2*((size_t)E + e)]; }
      if ((unsigned)d[i] >= (unsigned)N || (unsigned)s[i] >= (unsigned)N) d[i] = -1;
    }
  }
  #pragma unroll
  for (int i=0;i<4;++i)
    if (d[i] >= 0) atomicAdd(&h[d[i]>>9], 1);
  __syncthreads();
  if (t < NB && h[t]) cur[t] = excl + atomicAdd(&gcur[t], h[t]);
  __syncthreads();
  #pragma unroll
  for (int i=0;i<4;++i){
    if (d[i] >= 0){
      int p = atomicAdd(&cur[d[i]>>9], 1);
      pairs[p] = ((unsigned int)(d[i] & 511) << 17) | (unsigned int)s[i];
    }
  }
}

__global__ __launch_bounds__(1024) void k_bcsr(const unsigned int* __restrict__ pairs, const int* __restrict__ ghist,
                                               int* __restrict__ offs, int* __restrict__ csr, int N, int NB){
  __shared__ int sv[256];
  __shared__ int cnt[512];
  __shared__ int wsum[4];
  int b = blockIdx.x, t = threadIdx.x, lane = t&63, wv = t>>6;
  if (t < 256) sv[t] = ghist[t];
  __syncthreads();
  for (int o=1;o<256;o<<=1){
    int xv = (t>=o && t<256)? sv[t-o] : 0;
    __syncthreads();
    if (t < 256) sv[t] += xv;
    __syncthreads();
  }
  int lo = (b==0) ? 0 : sv[b-1];
  int hi = sv[b];
  int node0 = b << 9;
  if (t < 512) cnt[t] = 0;
  __syncthreads();
  for (int i = lo+t; i < hi; i += 1024){
    unsigned int p = pairs[i];
    atomicAdd(&cnt[p >> 17], 1);
  }
  __syncthreads();
  int v0 = 0, v1 = 0, tot = 0, s = 0;
  if (t < 256){
    v0 = cnt[2*t]; v1 = cnt[2*t+1]; tot = v0+v1;
    s = tot;
    #pragma unroll
    for (int o=1;o<64;o<<=1){ int xv = __shfl_up(s,o); if (lane>=o) s += xv; }
    if (lane==63) wsum[wv] = s;
  }
  __syncthreads();
  if (t < 256){
    int basev = 0;
    for (int j=0;j<wv;++j) basev += wsum[j];
    int excl = basev + s - tot;
    int e0 = lo + excl, e1 = lo + excl + v0;
    cnt[2*t] = e0; cnt[2*t+1] = e1;
    int n0 = node0 + 2*t, n1 = node0 + 2*t + 1;
    if (n0 < N) offs[n0] = e0;
    if (n1 < N) offs[n1] = e1;
  }
  if (b == NB-1 && t == 255) offs[N] = hi;
  __syncthreads();
  for (int i = lo+t; i < hi; i += 1024){
    unsigned int p = pairs[i];
    int pos = atomicAdd(&cnt[p >> 17], 1);
    csr[pos] = (int)(p & 0x1FFFFu);
  }
}

// ------------- standalone gather (layer 2, F=128): shfl-distributed csr + uint4 rows -------------

template<int F>
__global__ __launch_bounds__(256) void k_gatherx(const uint4* __restrict__ xr, const int* __restrict__ offs,
                                                 const int* __restrict__ csr, const float* __restrict__ epsp,
                                                 uint4* __restrict__ hr, int n, int nzrow){
  constexpr int RS  = F/8;
  constexpr int LPN = 4*RS;
  constexpr int NPW = 64/LPN;
  constexpr int CH  = LPN;
  constexpr int MAXG = CH/16;
  int gt = blockIdx.x*256 + threadIdx.x;
  int wv = gt >> 6, lane = gt & 63;
  int grp = lane / LPN;
  int lin = lane % LPN;
  int q   = lin / RS;
  int f   = lin % RS;
  int node = wv*NPW + grp;
  if (node >= n) return;
  const size_t row = (size_t)node*RS;
  float e1s = 1.0f + epsp[0];
  floatx2 a0,a1,a2,a3;
  if (q == 0){
    uint4 sv = xr[row + f];
    floatx2 es; es.x = e1s; es.y = e1s;
    a0 = es*bfpair(sv.x); a1 = es*bfpair(sv.y);
    a2 = es*bfpair(sv.z); a3 = es*bfpair(sv.w);
  } else {
    floatx2 z; z.x = 0.f; z.y = 0.f;
    a0 = z; a1 = z; a2 = z; a3 = z;
  }
  int u0 = offs[node], u1 = offs[node+1];
  int deg = u1 - u0;

#define ISSUE(g, V0,V1,V2,V3) { int bb = grp*LPN + (g)*16 + q; \
    int s0=__shfl(cv,bb), s1=__shfl(cv,bb+4), s2=__shfl(cv,bb+8), s3=__shfl(cv,bb+12); \
    V0 = xr[(size_t)s0*RS + f]; V1 = xr[(size_t)s1*RS + f]; \
    V2 = xr[(size_t)s2*RS + f]; V3 = xr[(size_t)s3*RS + f]; }
#define ACCV(V)  { a0 += bfpair((V).x); a1 += bfpair((V).y); a2 += bfpair((V).z); a3 += bfpair((V).w); }
#define ACC4(V0,V1,V2,V3) { ACCV(V0) ACCV(V1) ACCV(V2) ACCV(V3) }

  for (int c0 = 0; c0 < deg; c0 += CH){
    int rem = deg - c0;
    int cv = nzrow;
    if (lin < rem) cv = csr[u0 + c0 + lin];
    int nk = rem < CH ? rem : CH;
    int ng = (nk + 15) >> 4;
    uint4 A0,A1,A2,A3, B0,B1,B2,B3;
    ISSUE(0, A0,A1,A2,A3)
    if (ng > 1) { ISSUE(1, B0,B1,B2,B3) }
    ACC4(A0,A1,A2,A3)
    if (ng > 1){
      if constexpr (MAXG >= 3) { if (ng > 2) ISSUE(2, A0,A1,A2,A3) }
      ACC4(B0,B1,B2,B3)
      if constexpr (MAXG >= 3){
        if (ng > 2){
          if (ng > 3) { ISSUE(3, B0,B1,B2,B3) }
          ACC4(A0,A1,A2,A3)
          if (ng > 3) { ACC4(B0,B1,B2,B3) }
        }
      }
    }
  }
#undef ISSUE
#undef ACCV
#undef ACC4
#define RED(av) { av.x += __shfl_xor(av.x, RS);   av.y += __shfl_xor(av.y, RS); \
                  av.x += __shfl_xor(av.x, 2*RS); av.y += __shfl_xor(av.y, 2*RS); }
  RED(a0) RED(a1) RED(a2) RED(a3)
#undef RED
  if (q == 0){
    uint4 o;
    o.x = pack2(f2bf(a0.x), f2bf(a0.y));
    o.y = pack2(f2bf(a1.x), f2bf(a1.y));
    o.z = pack2(f2bf(a2.x), f2bf(a2.y));
    o.w = pack2(f2bf(a3.x), f2bf(a3.y));
    hr[row + f] = o;
  }
}

// ---------------- fused gather + MFMA MLP (layers 1 and 3, F=64), LDS-UNION version ----------------
// r7 failed at 31% occupancy (sH 9.2KB + sC1 17.4KB = 26.6KB LDS). Fix: sH and sC1 are not
// simultaneously live -- after the gather, each thread preloads its ENTIRE GEMM1 A-operand
// (KC1=2 short8 = 8 VGPRs) to registers, barriers, then sC1 overwrites the same LDS region.
// Union = max(9.2, 17.4) = 17.4 KB -> ~6 blocks/CU (vs 4), expected occupancy ~60-75%.
// Gather math identical to k_gatherx (same f2bf rounding into sH as into hbuf) => bit-identical.

template<int F, int M1, int M2, bool LAST>
__global__ __launch_bounds__(256)
void k_gmlp(const uint4* __restrict__ xr, const int* __restrict__ offs,
            const int* __restrict__ csr, const float* __restrict__ epsp,
            const ushort_t* __restrict__ wp1, const float* __restrict__ b1,
            const ushort_t* __restrict__ wp2, const float* __restrict__ b2,
            ushort_t* __restrict__ xout,
            float* __restrict__ embp,
            const ushort_t* __restrict__ wpfc, const float* __restrict__ bfc,
            float* __restrict__ outp, int n)
{
  constexpr int RS  = F/8;
  constexpr int LPN = 4*RS;
  constexpr int NPW = 64/LPN;
  constexpr int CH  = LPN;
  constexpr int MAXG = CH/16;
  constexpr int NPR = 4*NPW;          // nodes per round (all 4 waves)
  constexpr int PADC = F + 8;         // sH row stride (shorts)
  constexpr int NT1 = M1/16, NT2 = M2/16, KC1 = F/32, KC2 = M1/32;
  static_assert(KC1 == 2, "a-frag preload written for KC1==2");
  // union: gather-phase sH (64*PADC shorts) and MLP-phase sC1(+sX3) share storage
  constexpr int SC1_SZ = 4*(M1/8)*136;
  constexpr int SX3_SZ = LAST ? (4*8*136) : 0;
  constexpr int UNION_SZ = (64*PADC > SC1_SZ + SX3_SZ) ? 64*PADC : (SC1_SZ + SX3_SZ);

  __shared__ short sU[UNION_SZ] __attribute__((aligned(16)));
  short* sH  = sU;
  short* sC1 = sU;
  short* sX3 = sU + SC1_SZ;

  int tid = threadIdx.x, lane = tid&63, w = tid>>6;
  int node0 = blockIdx.x*64;

  // ---- gather phase (identical math to k_gatherx; invalid nodes clamp to zero row n) ----
  {
    int grp = lane / LPN;
    int lin = lane % LPN;
    int q   = lin / RS;
    int f   = lin % RS;
    float e1s = 1.0f + epsp[0];
    #pragma unroll
    for (int rd = 0; rd < 64/NPR; ++rd){
      int lrow = rd*NPR + w*NPW + grp;
      int node = node0 + lrow;
      int nd = node < n ? node : n;            // row n = zeros
      floatx2 a0,a1,a2,a3;
      if (q == 0){
        uint4 sv = xr[(size_t)nd*RS + f];
        floatx2 es; es.x = e1s; es.y = e1s;
        a0 = es*bfpair(sv.x); a1 = es*bfpair(sv.y);
        a2 = es*bfpair(sv.z); a3 = es*bfpair(sv.w);
      } else {
        floatx2 z; z.x = 0.f; z.y = 0.f;
        a0 = z; a1 = z; a2 = z; a3 = z;
      }
      int u0 = 0, deg = 0;
      if (node < n){ u0 = offs[node]; deg = offs[node+1] - u0; }

#define ISSUE(g, V0,V1,V2,V3) { int bb = grp*LPN + (g)*16 + q; \
    int s0=__shfl(cv,bb), s1=__shfl(cv,bb+4), s2=__shfl(cv,bb+8), s3=__shfl(cv,bb+12); \
    V0 = xr[(size_t)s0*RS + f]; V1 = xr[(size_t)s1*RS + f]; \
    V2 = xr[(size_t)s2*RS + f]; V3 = xr[(size_t)s3*RS + f]; }
#define ACCV(V)  { a0 += bfpair((V).x); a1 += bfpair((V).y); a2 += bfpair((V).z); a3 += bfpair((V).w); }
#define ACC4(V0,V1,V2,V3) { ACCV(V0) ACCV(V1) ACCV(V2) ACCV(V3) }
      for (int c0 = 0; c0 < deg; c0 += CH){
        int rem = deg - c0;
        int cv = n;
        if (lin < rem) cv = csr[u0 + c0 + lin];
        int nk = rem < CH ? rem : CH;
        int ng = (nk + 15) >> 4;
        uint4 A0,A1,A2,A3, B0,B1,B2,B3;
        ISSUE(0, A0,A1,A2,A3)
        if (ng > 1) { ISSUE(1, B0,B1,B2,B3) }
        ACC4(A0,A1,A2,A3)
        if (ng > 1){
          if constexpr (MAXG >= 3) { if (ng > 2) ISSUE(2, A0,A1,A2,A3) }
          ACC4(B0,B1,B2,B3)
          if constexpr (MAXG >= 3){
            if (ng > 2){
              if (ng > 3) { ISSUE(3, B0,B1,B2,B3) }
              ACC4(A0,A1,A2,A3)
              if (ng > 3) { ACC4(B0,B1,B2,B3) }
            }
          }
        }
      }
#undef ISSUE
#undef ACCV
#undef ACC4
#define RED(av) { av.x += __shfl_xor(av.x, RS);   av.y += __shfl_xor(av.y, RS); \
                  av.x += __shfl_xor(av.x, 2*RS); av.y += __shfl_xor(av.y, 2*RS); }
      RED(a0) RED(a1) RED(a2) RED(a3)
#undef RED
      if (q == 0){
        uint4 o;
        o.x = pack2(f2bf(a0.x), f2bf(a0.y));
        o.y = pack2(f2bf(a1.x), f2bf(a1.y));
        o.z = pack2(f2bf(a2.x), f2bf(a2.y));
        o.w = pack2(f2bf(a3.x), f2bf(a3.y));
        *(uint4*)&sH[lrow*PADC + f*8] = o;
      }
    }
  }
  __syncthreads();

  // ---- preload GEMM1 A-fragments to registers (frees sH for reuse as sC1) ----
  int m16 = lane&15, quad = lane>>4;
  int row0 = node0 + w*16;
  short8 aR0 = *(const short8*)&sH[(w*16 + m16)*PADC + 0*32 + quad*8];
  short8 aR1 = *(const short8*)&sH[(w*16 + m16)*PADC + 1*32 + quad*8];
  __syncthreads();

  // ---- GEMM1 (A from regs) -> bias/relu -> sC1 (overwrites sH region) ----
  floatx4 acc[NT1];
  #pragma unroll
  for (int i=0;i<NT1;++i) acc[i] = (floatx4){0.f,0.f,0.f,0.f};
  #pragma unroll
  for (int nt=0; nt<NT1; ++nt){
    short8 b0 = *(const short8*)(wp1 + (size_t)((nt*KC1+0)*64 + lane)*8);
    acc[nt] = __builtin_amdgcn_mfma_f32_16x16x32_bf16(aR0, b0, acc[nt], 0, 0, 0);
    short8 b1v = *(const short8*)(wp1 + (size_t)((nt*KC1+1)*64 + lane)*8);
    acc[nt] = __builtin_amdgcn_mfma_f32_16x16x32_bf16(aR1, b1v, acc[nt], 0, 0, 0);
  }
  #pragma unroll
  for (int nt=0; nt<NT1; ++nt){
    int c = nt*16 + m16;
    float bias = b1[c];
    #pragma unroll
    for (int r=0;r<4;++r){
      float v = fmaxf(acc[nt][r] + bias, 0.f);
      int mm = quad*4 + r;
      sC1[(w*(M1/8) + (c>>3))*136 + mm*8 + (c&7)] = (short)f2bf(v);
    }
  }
  __syncthreads();

  // ---- GEMM2 ----
  floatx4 acc2[NT2];
  #pragma unroll
  for (int i=0;i<NT2;++i) acc2[i] = (floatx4){0.f,0.f,0.f,0.f};
  #pragma unroll
  for (int kc=0; kc<KC2; ++kc){
    short8 a = *(const short8*)&sC1[(w*(M1/8) + kc*4 + quad)*136 + m16*8];
    #pragma unroll
    for (int nt=0; nt<NT2; ++nt){
      short8 b = *(const short8*)(wp2 + (size_t)((nt*KC2+kc)*64 + lane)*8);
      acc2[nt] = __builtin_amdgcn_mfma_f32_16x16x32_bf16(a, b, acc2[nt], 0, 0, 0);
    }
  }
  #pragma unroll
  for (int nt=0; nt<NT2; ++nt){
    int c = nt*16 + m16;
    float bias = b2[c];
    #pragma unroll
    for (int r=0;r<4;++r){
      float v = fmaxf(acc2[nt][r] + bias, 0.f);
      int mm = quad*4 + r;
      int row = row0 + mm;
      if constexpr (!LAST){
        if (row < n) xout[(size_t)row*M2 + c] = f2bf(v);
      } else {
        if (row < n) embp[(size_t)row*64 + c] = v;                // f32 emb
        sX3[(w*8 + (c>>3))*136 + mm*8 + (c&7)] = (short)f2bf(v);
      }
    }
  }

  if constexpr (LAST){
    __syncthreads();
    floatx4 accf = (floatx4){0.f,0.f,0.f,0.f};
    #pragma unroll
    for (int kc=0; kc<2; ++kc){
      short8 a = *(const short8*)&sX3[(w*8 + kc*4 + quad)*136 + m16*8];
      short8 b = *(const short8*)(wpfc + (size_t)(kc*64 + lane)*8);
      accf = __builtin_amdgcn_mfma_f32_16x16x32_bf16(a, b, accf, 0, 0, 0);
    }
    if (m16 < 8){
      float bias = bfc[m16];
      #pragma unroll
      for (int r=0;r<4;++r){
        int row = row0 + quad*4 + r;
        if (row < n) outp[(size_t)row*8 + m16] = accf[r] + bias;  // f32 out
      }
    }
  }
}

// ---------------- standalone MFMA MLP (layer 2, reads hbuf) ----------------

template<int F, int M1, int M2, bool LAST, bool Y3>
__global__ __launch_bounds__(256)
void k_mlp(const ushort_t* __restrict__ h,
           const ushort_t* __restrict__ wp1, const float* __restrict__ b1,
           const ushort_t* __restrict__ wp2, const float* __restrict__ b2,
           ushort_t* __restrict__ xout,
           float* __restrict__ embp,
           const ushort_t* __restrict__ wpfc, const float* __restrict__ bfc,
           float* __restrict__ outp, int n)
{
  constexpr int NT1 = M1/16, NT2 = M2/16, KC1 = F/32, KC2 = M1/32;
  __shared__ short sC1[4*(M1/8)*136];
  __shared__ short sX3[LAST ? (4*8*136) : 1];
  int tid = threadIdx.x, lane = tid&63, w = tid>>6;
  int m16 = lane&15, quad = lane>>4;
  int row0 = blockIdx.x*64 + w*16;
  size_t arow = (size_t)(row0 + m16);

  floatx4 acc[NT1];
  #pragma unroll
  for (int i=0;i<NT1;++i) acc[i] = (floatx4){0.f,0.f,0.f,0.f};
  #pragma unroll
  for (int kc=0; kc<KC1; ++kc){
    short8 a = *(const short8*)(h + arow*F + kc*32 + quad*8);
    #pragma unroll
    for (int nt=0; nt<NT1; ++nt){
      short8 b = *(const short8*)(wp1 + (size_t)((nt*KC1+kc)*64 + lane)*8);
      acc[nt] = __builtin_amdgcn_mfma_f32_16x16x32_bf16(a, b, acc[nt], 0, 0, 0);
    }
  }
  #pragma unroll
  for (int nt=0; nt<NT1; ++nt){
    int c = nt*16 + m16;
    float bias = b1[c];
    #pragma unroll
    for (int r=0;r<4;++r){
      float v = fmaxf(acc[nt][r] + bias, 0.f);
      int mm = quad*4 + r;
      sC1[(w*(M1/8) + (c>>3))*136 + mm*8 + (c&7)] = (short)f2bf(v);
    }
  }
  __syncthreads();

  floatx4 acc2[NT2];
  #pragma unroll
  for (int i=0;i<NT2;++i) acc2[i] = (floatx4){0.f,0.f,0.f,0.f};
  #pragma unroll
  for (int kc=0; kc<KC2; ++kc){
    short8 a = *(const short8*)&sC1[(w*(M1/8) + kc*4 + quad)*136 + m16*8];
    #pragma unroll
    for (int nt=0; nt<NT2; ++nt){
      short8 b = *(const short8*)(wp2 + (size_t)((nt*KC2+kc)*64 + lane)*8);
      acc2[nt] = __builtin_amdgcn_mfma_f32_16x16x32_bf16(a, b, acc2[nt], 0, 0, 0);
    }
  }
  #pragma unroll
  for (int nt=0; nt<NT2; ++nt){
    int c = nt*16 + m16;
    float bias = b2[c];
    #pragma unroll
    for (int r=0;r<4;++r){
      float v = fmaxf(acc2[nt][r] + bias, 0.f);
      int mm = quad*4 + r;
      int row = row0 + mm;
      if constexpr (Y3){
        sC1[(w*(M2/8) + (c>>3))*136 + mm*8 + (c&7)] = (short)f2bf(v);
      } else if constexpr (!LAST){
        if (row < n) xout[(size_t)row*M2 + c] = f2bf(v);
      } else {
        if (row < n) embp[(size_t)row*64 + c] = v;
        sX3[(w*8 + (c>>3))*136 + mm*8 + (c&7)] = (short)f2bf(v);
      }
    }
  }

  if constexpr (Y3){
    constexpr int KC3 = M2/32;
    floatx4 acc3[4];
    #pragma unroll
    for (int i=0;i<4;++i) acc3[i] = (floatx4){0.f,0.f,0.f,0.f};
    #pragma unroll
    for (int kc=0; kc<KC3; ++kc){
      short8 a = *(const short8*)&sC1[(w*(M2/8) + kc*4 + quad)*136 + m16*8];
      #pragma unroll
      for (int nt=0; nt<4; ++nt){
        short8 b = *(const short8*)(wpfc + (size_t)((nt*KC3+kc)*64 + lane)*8);
        acc3[nt] = __builtin_amdgcn_mfma_f32_16x16x32_bf16(a, b, acc3[nt], 0, 0, 0);
      }
    }
    #pragma unroll
    for (int nt=0; nt<4; ++nt){
      int c = nt*16 + m16;
      #pragma unroll
      for (int r=0;r<4;++r){
        int row = row0 + quad*4 + r;
        if (row < n) xout[(size_t)row*64 + c] = f2bf(acc3[nt][r]);
      }
    }
  }

  if constexpr (LAST){
    __syncthreads();
    floatx4 accf = (floatx4){0.f,0.f,0.f,0.f};
    #pragma unroll
    for (int kc=0; kc<2; ++kc){
      short8 a = *(const short8*)&sX3[(w*8 + kc*4 + quad)*136 + m16*8];
      short8 b = *(const short8*)(wpfc + (size_t)(kc*64 + lane)*8);
      accf = __builtin_amdgcn_mfma_f32_16x16x32_bf16(a, b, accf, 0, 0, 0);
    }
    if (m16 < 8){
      float bias = bfc[m16];
      #pragma unroll
      for (int r=0;r<4;++r){
        int row = row0 + quad*4 + r;
        if (row < n) outp[(size_t)row*8 + m16] = accf[r] + bias;
      }
    }
  }
}

// ---------------- launcher ----------------

extern "C" void kernel_launch(void* const* d_in, const int* in_sizes, int n_in,
                              void* d_out, int out_size, void* d_ws, size_t ws_size,
                              hipStream_t stream)
{
  const int N = in_sizes[0] / 64;
  const int E = in_sizes[1] / 2;
  const int NB = (N + 511) / 512;
  const float*        x    = (const float*)d_in[0];
  const unsigned int* ew   = (const unsigned int*)d_in[1];
  const float* eps1 = (const float*)d_in[2];
  const float* eps2 = (const float*)d_in[3];
  const float* eps3 = (const float*)d_in[4];
  const float* W1a  = (const float*)d_in[5];
  const float* b1a  = (const float*)d_in[6];
  const float* W1b  = (const float*)d_in[7];
  const float* b1b  = (const float*)d_in[8];
  const float* W2a  = (const float*)d_in[9];
  const float* b2a  = (const float*)d_in[10];
  const float* W2b  = (const float*)d_in[11];
  const float* b2b  = (const float*)d_in[12];
  const float* W3a  = (const float*)d_in[13];
  const float* b3a  = (const float*)d_in[14];
  const float* W3b  = (const float*)d_in[15];
  const float* b3b  = (const float*)d_in[16];
  const float* Wfc  = (const float*)d_in[17];
  const float* bfc  = (const float*)d_in[18];

  float* outp = (float*)d_out;                 // f32 output
  float* emb  = outp + (size_t)N*8;

  const int Npad = ((N + 63)/64)*64;
  const int nbB  = (E + 4095)/4096;

  char* ws = (char*)d_ws;
  size_t o = 0;
  auto alloc = [&](size_t bytes)->char* {
    char* p = ws + o;
    o = (o + bytes + 255) & ~(size_t)255;
    return p;
  };
  int*      ghist = (int*)alloc(512*4);                            // [0:256) hist, [256:512) gcur
  int*      gcur  = ghist + 256;
  int*      dflag = (int*)alloc((size_t)nbB*4);
  int*      offs  = (int*)alloc((size_t)(N+1)*4);
  unsigned int* pairs = (unsigned int*)alloc((size_t)E*4);         // packed (dloc:9 | src:17)
  int*      csr   = (int*)alloc((size_t)E*4);
  ushort_t* wperm = (ushort_t*)alloc(74752ull*2);
  ushort_t* xb    = (ushort_t*)alloc(((size_t)Npad + 64)*64*2);    // bf16 x (+zero row N)
  ushort_t* hbuf  = (ushort_t*)alloc((size_t)Npad*128*2);          // layer-2 gather output
  ushort_t* x1    = (ushort_t*)alloc(((size_t)Npad + 64)*128*2);   // layer-1 output (+zero row N)
  ushort_t* ybuf  = (ushort_t*)alloc(((size_t)Npad + 64)*64*2);    // y3 = x2@W3a (+zero row N)

  hipMemsetAsync(ghist, 0, 512*4, stream);                         // hist + gcur
  const int tobfB = (N*32 + 1023)/1024;
  const int permB = (74752 + 256 + 1023)/1024;
  k_prep<<<nbB + tobfB + permB, 1024, 0, stream>>>(ew, ghist, dflag, E, N, nbB,
                                                   (const float2*)x, (unsigned int*)xb, N*32, tobfB,
                                                   W1a, W1b, W2a, W2b, W3a, W3b, Wfc, wperm,
                                                   xb + (size_t)N*64, x1 + (size_t)N*128, ybuf + (size_t)N*64);
  k_bin<<<nbB, 1024, 0, stream>>>(ew, ghist, dflag, gcur, pairs, E, N, NB);
  k_bcsr<<<NB, 1024, 0, stream>>>(pairs, ghist, offs, csr, N, NB);

  // layer 1 (64 -> 128): fused gather(F=64) + MLP (LDS-union), writes x1 row-major
  k_gmlp<64,128,128,false><<<Npad/64, 256, 0, stream>>>((const uint4*)xb, offs, csr, eps1,
                                                        wperm+0, b1a, wperm+8192, b1b,
                                                        x1, nullptr, nullptr, nullptr, nullptr, N);
  // layer 2 (128 -> 128): standalone row gather + MLP with y3 = x2@W3a pre-transform
  k_gatherx<128><<<(N+3)/4, 256, 0, stream>>>((const uint4*)x1, offs, csr, eps2,
                                              (uint4*)hbuf, N, N);
  k_mlp<128,128,128,false,true><<<Npad/64, 256, 0, stream>>>(hbuf, wperm+24576, b2a, wperm+40960, b2b,
                                                             ybuf, nullptr, wperm+57344, nullptr, nullptr, N);
  // layer 3: fused gather(F=64) on y3 + identity-GEMM1 (bias+relu) + W3b + FC
  k_gmlp<64,64,64,true><<<Npad/64, 256, 0, stream>>>((const uint4*)ybuf, offs, csr, eps3,
                                                     wperm+70656, b3a, wperm+65536, b3b,
                                                     nullptr, emb, wperm+69632, bfc, outp, N);
}

// Round 12
// 338.870 us; speedup vs baseline: 1.0188x; 1.0188x over previous
//
#include <hip/hip_runtime.h>
#include <hip/hip_bf16.h>
#include <stdint.h>

typedef unsigned short ushort_t;
typedef __attribute__((ext_vector_type(8))) short short8;
typedef __attribute__((ext_vector_type(4))) float floatx4;
typedef __attribute__((ext_vector_type(2))) float floatx2;

__device__ __forceinline__ unsigned short f2bf(float f){
  union { float f; unsigned int i; } v; v.f = f;
  unsigned int r = v.i + 0x7FFFu + ((v.i >> 16) & 1u);
  return (unsigned short)(r >> 16);
}
__device__ __forceinline__ unsigned int pack2(unsigned short lo, unsigned short hi){
  return ((unsigned int)hi << 16) | (unsigned int)lo;
}
// packed bf16-pair -> float2; accumulate via packed f32 add
__device__ __forceinline__ floatx2 bfpair(unsigned int v){
  union { unsigned int u; float f; } lo, hi;
  lo.u = v << 16; hi.u = v & 0xffff0000u;
  floatx2 r; r.x = lo.f; r.y = hi.f; return r;
}

// ---------------- prep kernel (1024 thr): [hist + dflag | x->bf16 | weight perm + zero rows] ----------------
// Per-block int64/int32 storage detect: OR 4096 odd words of this block's span
// (int64 storage => all-zero high halves; P(false positive | int32) ~ 0).
// dflag[b] caches detect for k_bin (1:1 block/edge-span mapping).

__global__ __launch_bounds__(1024)
void k_prep(const unsigned int* __restrict__ w, int* __restrict__ ghist, int* __restrict__ dflag,
            int E, int N, int nbB,
            const float2* __restrict__ xin, unsigned int* __restrict__ xb, int total2, int tobfB,
            const float* __restrict__ W1a, const float* __restrict__ W1b, const float* __restrict__ W2a,
            const float* __restrict__ W2b, const float* __restrict__ W3a, const float* __restrict__ W3b,
            const float* __restrict__ Wfc, ushort_t* __restrict__ wout,
            ushort_t* __restrict__ xbz, ushort_t* __restrict__ x1z, ushort_t* __restrict__ ybz)
{
  int b = blockIdx.x, t = threadIdx.x;
  if (b < nbB){
    __shared__ int h[256];
    __shared__ unsigned int dred[16];
    if (t < 256) h[t] = 0;
    int base = b*4096 + t;
    unsigned int acc = 0;
    #pragma unroll
    for (int i=0;i<4;++i){
      int e = base + i*1024;
      if (e < E) acc |= w[2*e+1];
    }
    #pragma unroll
    for (int o=32;o>=1;o>>=1) acc |= __shfl_xor(acc, o);
    if ((t&63)==0) dred[t>>6] = acc;
    __syncthreads();
    unsigned int mm = 0;
    #pragma unroll
    for (int i=0;i<16;++i) mm |= dred[i];
    int m = mm != 0;                          // 1 => int32 words
    if (t == 0) dflag[b] = m;
    #pragma unroll
    for (int i=0;i<4;++i){
      int e = base + i*1024;
      if (e < E){
        int d = m ? (int)w[(size_t)E + e] : (int)w[2*((size_t)E + e)];
        if ((unsigned)d < (unsigned)N) atomicAdd(&h[d>>9], 1);
      }
    }
    __syncthreads();
    if (t < 256 && h[t]) atomicAdd(&ghist[t], h[t]);
  } else if (b < nbB + tobfB){
    int i = (b - nbB)*1024 + t;
    if (i < total2){
      float2 v = xin[i];
      xb[i] = pack2(f2bf(v.x), f2bf(v.y));
    }
  } else {
    int id = (b - nbB - tobfB)*1024 + t;
    if (id >= 74752){
      int id2 = id - 74752;
      if      (id2 <  64) xbz[id2]      = 0;   // xb zero row (64)
      else if (id2 < 192) x1z[id2-64]   = 0;   // x1 zero row (128)
      else if (id2 < 256) ybz[id2-192]  = 0;   // ybuf zero row (64)
      return;
    }
    const float* src; int K, M, base2, local;
    if      (id <  8192){ src=W1a; K=64;  M=128; base2=0;     local=id; }
    else if (id < 24576){ src=W1b; K=128; M=128; base2=8192;  local=id-8192; }
    else if (id < 40960){ src=W2a; K=128; M=128; base2=24576; local=id-24576; }
    else if (id < 57344){ src=W2b; K=128; M=128; base2=40960; local=id-40960; }
    else if (id < 65536){ src=W3a; K=128; M=64;  base2=57344; local=id-57344; }
    else if (id < 69632){ src=W3b; K=64;  M=64;  base2=65536; local=id-65536; }
    else if (id < 70656){ src=Wfc; K=64;  M=16;  base2=69632; local=id-69632; }
    else                { src=nullptr; K=64; M=64; base2=70656; local=id-70656; } // identity
    int k = local / M, nn = local - k*M;
    float val;
    if (src == nullptr) val = (k == nn) ? 1.0f : 0.0f;
    else if (src == Wfc) val = (nn<8) ? Wfc[k*8+nn] : 0.0f;
    else                 val = src[k*M+nn];
    int idx = (((nn>>4)*(K/32) + (k>>5))*4 + ((k>>3)&3))*128 + (nn&15)*8 + (k&7);
    wout[base2+idx] = f2bf(val);
  }
}

// ---------------- CSR build via 512-node bucket counting sort (1024-thread blocks) ----------------
// pairs packed u32: (dloc:9 | src:17) -- valid for N < 131072 (problem N = 100000).

__global__ __launch_bounds__(1024) void k_bin(const unsigned int* __restrict__ w,
                                              const int* __restrict__ ghist, const int* __restrict__ dflag,
                                              int* __restrict__ gcur,
                                              unsigned int* __restrict__ pairs,
                                              int E, int N, int NB){
  __shared__ int sv[256];
  __shared__ int h[256];
  __shared__ int cur[256];
  int t = threadIdx.x;
  int gv = 0;
  if (t < 256){ gv = ghist[t]; sv[t] = gv; }
  __syncthreads();
  for (int o=1;o<256;o<<=1){
    int xv = (t>=o && t<256)? sv[t-o] : 0;
    __syncthreads();
    if (t < 256) sv[t] += xv;
    __syncthreads();
  }
  int excl = (t < 256) ? sv[t] - gv : 0;
  if (t < 256) h[t] = 0;
  int m = dflag[blockIdx.x];
  int base = blockIdx.x*4096 + t;
  __syncthreads();
  int d[4], s[4];
  #pragma unroll
  for (int i=0;i<4;++i){
    int e = base + i*1024;
    d[i] = -1; s[i] = 0;
    if (e < E){
      if (m){ s[i] = (int)w[e];           d[i] = (int)w[(size_t)E + e]; }
      else  { s[i] = (int)w[2*(size_t)e]; d[i] = (int)w[2*((size_t)E + e)]; }
      if ((unsigned)d[i] >= (unsigned)N || (unsigned)s[i] >= (unsigned)N) d[i] = -1;
    }
  }
  #pragma unroll
  for (int i=0;i<4;++i)
    if (d[i] >= 0) atomicAdd(&h[d[i]>>9], 1);
  __syncthreads();
  if (t < NB && h[t]) cur[t] = excl + atomicAdd(&gcur[t], h[t]);
  __syncthreads();
  #pragma unroll
  for (int i=0;i<4;++i){
    if (d[i] >= 0){
      int p = atomicAdd(&cur[d[i]>>9], 1);
      pairs[p] = ((unsigned int)(d[i] & 511) << 17) | (unsigned int)s[i];
    }
  }
}

__global__ __launch_bounds__(1024) void k_bcsr(const unsigned int* __restrict__ pairs, const int* __restrict__ ghist,
                                               int* __restrict__ offs, int* __restrict__ csr, int N, int NB){
  __shared__ int sv[256];
  __shared__ int cnt[512];
  __shared__ int wsum[4];
  int b = blockIdx.x, t = threadIdx.x, lane = t&63, wv = t>>6;
  if (t < 256) sv[t] = ghist[t];
  __syncthreads();
  for (int o=1;o<256;o<<=1){
    int xv = (t>=o && t<256)? sv[t-o] : 0;
    __syncthreads();
    if (t < 256) sv[t] += xv;
    __syncthreads();
  }
  int lo = (b==0) ? 0 : sv[b-1];
  int hi = sv[b];
  int node0 = b << 9;
  if (t < 512) cnt[t] = 0;
  __syncthreads();
  for (int i = lo+t; i < hi; i += 1024){
    unsigned int p = pairs[i];
    atomicAdd(&cnt[p >> 17], 1);
  }
  __syncthreads();
  int v0 = 0, v1 = 0, tot = 0, s = 0;
  if (t < 256){
    v0 = cnt[2*t]; v1 = cnt[2*t+1]; tot = v0+v1;
    s = tot;
    #pragma unroll
    for (int o=1;o<64;o<<=1){ int xv = __shfl_up(s,o); if (lane>=o) s += xv; }
    if (lane==63) wsum[wv] = s;
  }
  __syncthreads();
  if (t < 256){
    int basev = 0;
    for (int j=0;j<wv;++j) basev += wsum[j];
    int excl = basev + s - tot;
    int e0 = lo + excl, e1 = lo + excl + v0;
    cnt[2*t] = e0; cnt[2*t+1] = e1;
    int n0 = node0 + 2*t, n1 = node0 + 2*t + 1;
    if (n0 < N) offs[n0] = e0;
    if (n1 < N) offs[n1] = e1;
  }
  if (b == NB-1 && t == 255) offs[N] = hi;
  __syncthreads();
  for (int i = lo+t; i < hi; i += 1024){
    unsigned int p = pairs[i];
    int pos = atomicAdd(&cnt[p >> 17], 1);
    csr[pos] = (int)(p & 0x1FFFFu);
  }
}

// ------------- gather (both F): shfl-distributed csr + uint4 rows + packed-f32 accumulate -------------

template<int F>
__global__ __launch_bounds__(256) void k_gatherx(const uint4* __restrict__ xr, const int* __restrict__ offs,
                                                 const int* __restrict__ csr, const float* __restrict__ epsp,
                                                 uint4* __restrict__ hr, int n, int nzrow){
  constexpr int RS  = F/8;           // uint4 per row: 16 (F=128), 8 (F=64)
  constexpr int LPN = 4*RS;          // lanes per node
  constexpr int NPW = 64/LPN;        // nodes per wave
  constexpr int CH  = LPN;           // csr entries per chunk
  constexpr int MAXG = CH/16;        // groups per chunk
  int gt = blockIdx.x*256 + threadIdx.x;
  int wv = gt >> 6, lane = gt & 63;
  int grp = lane / LPN;              // node within wave
  int lin = lane % LPN;              // lane within node
  int q   = lin / RS;                // quarter 0..3
  int f   = lin % RS;                // uint4 index within row
  int node = wv*NPW + grp;
  if (node >= n) return;
  const size_t row = (size_t)node*RS;
  float e1s = 1.0f + epsp[0];
  floatx2 a0,a1,a2,a3;
  if (q == 0){
    uint4 sv = xr[row + f];
    floatx2 es; es.x = e1s; es.y = e1s;
    a0 = es*bfpair(sv.x); a1 = es*bfpair(sv.y);
    a2 = es*bfpair(sv.z); a3 = es*bfpair(sv.w);
  } else {
    floatx2 z; z.x = 0.f; z.y = 0.f;
    a0 = z; a1 = z; a2 = z; a3 = z;
  }
  int u0 = offs[node], u1 = offs[node+1];
  int deg = u1 - u0;

#define ISSUE(g, V0,V1,V2,V3) { int bb = grp*LPN + (g)*16 + q; \
    int s0=__shfl(cv,bb), s1=__shfl(cv,bb+4), s2=__shfl(cv,bb+8), s3=__shfl(cv,bb+12); \
    V0 = xr[(size_t)s0*RS + f]; V1 = xr[(size_t)s1*RS + f]; \
    V2 = xr[(size_t)s2*RS + f]; V3 = xr[(size_t)s3*RS + f]; }
#define ACCV(V)  { a0 += bfpair((V).x); a1 += bfpair((V).y); a2 += bfpair((V).z); a3 += bfpair((V).w); }
#define ACC4(V0,V1,V2,V3) { ACCV(V0) ACCV(V1) ACCV(V2) ACCV(V3) }

  for (int c0 = 0; c0 < deg; c0 += CH){
    int rem = deg - c0;
    int cv = nzrow;                          // padded entries gather the zeroed row
    if (lin < rem) cv = csr[u0 + c0 + lin];  // one coalesced load covers the chunk
    int nk = rem < CH ? rem : CH;
    int ng = (nk + 15) >> 4;                 // uniform within a node
    uint4 A0,A1,A2,A3, B0,B1,B2,B3;
    ISSUE(0, A0,A1,A2,A3)
    if (ng > 1) { ISSUE(1, B0,B1,B2,B3) }
    ACC4(A0,A1,A2,A3)
    if (ng > 1){
      if constexpr (MAXG >= 3) { if (ng > 2) ISSUE(2, A0,A1,A2,A3) }
      ACC4(B0,B1,B2,B3)
      if constexpr (MAXG >= 3){
        if (ng > 2){
          if (ng > 3) { ISSUE(3, B0,B1,B2,B3) }
          ACC4(A0,A1,A2,A3)
          if (ng > 3) { ACC4(B0,B1,B2,B3) }
        }
      }
    }
  }
#undef ISSUE
#undef ACCV
#undef ACC4
#define RED(av) { av.x += __shfl_xor(av.x, RS);   av.y += __shfl_xor(av.y, RS); \
                  av.x += __shfl_xor(av.x, 2*RS); av.y += __shfl_xor(av.y, 2*RS); }
  RED(a0) RED(a1) RED(a2) RED(a3)
#undef RED
  if (q == 0){
    uint4 o;
    o.x = pack2(f2bf(a0.x), f2bf(a0.y));
    o.y = pack2(f2bf(a1.x), f2bf(a1.y));
    o.z = pack2(f2bf(a2.x), f2bf(a2.y));
    o.w = pack2(f2bf(a3.x), f2bf(a3.y));
    hr[row + f] = o;
  }
}

// ---------------- fused MFMA MLP ----------------
// x_next = relu(relu(h@Wa+ba)@Wb+bb)
// Y3:   additionally y3 = x_next @ W3a (wpfc = W3a-perm, 128->64, linear only); ONLY y3 written.
// LAST: emb(f32) + FC GEMM -> out(f32).

template<int F, int M1, int M2, bool LAST, bool Y3>
__global__ __launch_bounds__(256)
void k_mlp(const ushort_t* __restrict__ h,
           const ushort_t* __restrict__ wp1, const float* __restrict__ b1,
           const ushort_t* __restrict__ wp2, const float* __restrict__ b2,
           ushort_t* __restrict__ xout,
           float* __restrict__ embp,
           const ushort_t* __restrict__ wpfc, const float* __restrict__ bfc,
           float* __restrict__ outp, int n)
{
  constexpr int NT1 = M1/16, NT2 = M2/16, KC1 = F/32, KC2 = M1/32;
  __shared__ short sC1[4*(M1/8)*136];
  __shared__ short sX3[LAST ? (4*8*136) : 1];
  int tid = threadIdx.x, lane = tid&63, w = tid>>6;
  int m16 = lane&15, quad = lane>>4;
  int row0 = blockIdx.x*64 + w*16;
  size_t arow = (size_t)(row0 + m16);

  floatx4 acc[NT1];
  #pragma unroll
  for (int i=0;i<NT1;++i) acc[i] = (floatx4){0.f,0.f,0.f,0.f};
  #pragma unroll
  for (int kc=0; kc<KC1; ++kc){
    short8 a = *(const short8*)(h + arow*F + kc*32 + quad*8);
    #pragma unroll
    for (int nt=0; nt<NT1; ++nt){
      short8 b = *(const short8*)(wp1 + (size_t)((nt*KC1+kc)*64 + lane)*8);
      acc[nt] = __builtin_amdgcn_mfma_f32_16x16x32_bf16(a, b, acc[nt], 0, 0, 0);
    }
  }
  #pragma unroll
  for (int nt=0; nt<NT1; ++nt){
    int c = nt*16 + m16;
    float bias = b1[c];
    #pragma unroll
    for (int r=0;r<4;++r){
      float v = fmaxf(acc[nt][r] + bias, 0.f);
      int mm = quad*4 + r;
      sC1[(w*(M1/8) + (c>>3))*136 + mm*8 + (c&7)] = (short)f2bf(v);
    }
  }
  __syncthreads();

  floatx4 acc2[NT2];
  #pragma unroll
  for (int i=0;i<NT2;++i) acc2[i] = (floatx4){0.f,0.f,0.f,0.f};
  #pragma unroll
  for (int kc=0; kc<KC2; ++kc){
    short8 a = *(const short8*)&sC1[(w*(M1/8) + kc*4 + quad)*136 + m16*8];
    #pragma unroll
    for (int nt=0; nt<NT2; ++nt){
      short8 b = *(const short8*)(wp2 + (size_t)((nt*KC2+kc)*64 + lane)*8);
      acc2[nt] = __builtin_amdgcn_mfma_f32_16x16x32_bf16(a, b, acc2[nt], 0, 0, 0);
    }
  }
  #pragma unroll
  for (int nt=0; nt<NT2; ++nt){
    int c = nt*16 + m16;
    float bias = b2[c];
    #pragma unroll
    for (int r=0;r<4;++r){
      float v = fmaxf(acc2[nt][r] + bias, 0.f);
      int mm = quad*4 + r;
      int row = row0 + mm;
      if constexpr (Y3){
        sC1[(w*(M2/8) + (c>>3))*136 + mm*8 + (c&7)] = (short)f2bf(v);
      } else if constexpr (!LAST){
        if (row < n) xout[(size_t)row*M2 + c] = f2bf(v);
      } else {
        if (row < n) embp[(size_t)row*64 + c] = v;                // f32 emb
        sX3[(w*8 + (c>>3))*136 + mm*8 + (c&7)] = (short)f2bf(v);
      }
    }
  }

  if constexpr (Y3){
    // y3 = x2 @ W3a (M2=128 -> 64), linear only (bias+relu later via identity GEMM)
    constexpr int KC3 = M2/32;
    floatx4 acc3[4];
    #pragma unroll
    for (int i=0;i<4;++i) acc3[i] = (floatx4){0.f,0.f,0.f,0.f};
    #pragma unroll
    for (int kc=0; kc<KC3; ++kc){
      short8 a = *(const short8*)&sC1[(w*(M2/8) + kc*4 + quad)*136 + m16*8];
      #pragma unroll
      for (int nt=0; nt<4; ++nt){
        short8 b = *(const short8*)(wpfc + (size_t)((nt*KC3+kc)*64 + lane)*8);
        acc3[nt] = __builtin_amdgcn_mfma_f32_16x16x32_bf16(a, b, acc3[nt], 0, 0, 0);
      }
    }
    #pragma unroll
    for (int nt=0; nt<4; ++nt){
      int c = nt*16 + m16;
      #pragma unroll
      for (int r=0;r<4;++r){
        int row = row0 + quad*4 + r;
        if (row < n) xout[(size_t)row*64 + c] = f2bf(acc3[nt][r]);
      }
    }
  }

  if constexpr (LAST){
    __syncthreads();
    floatx4 accf = (floatx4){0.f,0.f,0.f,0.f};
    #pragma unroll
    for (int kc=0; kc<2; ++kc){
      short8 a = *(const short8*)&sX3[(w*8 + kc*4 + quad)*136 + m16*8];
      short8 b = *(const short8*)(wpfc + (size_t)(kc*64 + lane)*8);
      accf = __builtin_amdgcn_mfma_f32_16x16x32_bf16(a, b, accf, 0, 0, 0);
    }
    if (m16 < 8){
      float bias = bfc[m16];
      #pragma unroll
      for (int r=0;r<4;++r){
        int row = row0 + quad*4 + r;
        if (row < n) outp[(size_t)row*8 + m16] = accf[r] + bias;  // f32 out
      }
    }
  }
}

// ---------------- launcher ----------------

extern "C" void kernel_launch(void* const* d_in, const int* in_sizes, int n_in,
                              void* d_out, int out_size, void* d_ws, size_t ws_size,
                              hipStream_t stream)
{
  const int N = in_sizes[0] / 64;
  const int E = in_sizes[1] / 2;
  const int NB = (N + 511) / 512;
  const float*        x    = (const float*)d_in[0];
  const unsigned int* ew   = (const unsigned int*)d_in[1];
  const float* eps1 = (const float*)d_in[2];
  const float* eps2 = (const float*)d_in[3];
  const float* eps3 = (const float*)d_in[4];
  const float* W1a  = (const float*)d_in[5];
  const float* b1a  = (const float*)d_in[6];
  const float* W1b  = (const float*)d_in[7];
  const float* b1b  = (const float*)d_in[8];
  const float* W2a  = (const float*)d_in[9];
  const float* b2a  = (const float*)d_in[10];
  const float* W2b  = (const float*)d_in[11];
  const float* b2b  = (const float*)d_in[12];
  const float* W3a  = (const float*)d_in[13];
  const float* b3a  = (const float*)d_in[14];
  const float* W3b  = (const float*)d_in[15];
  const float* b3b  = (const float*)d_in[16];
  const float* Wfc  = (const float*)d_in[17];
  const float* bfc  = (const float*)d_in[18];

  float* outp = (float*)d_out;                 // f32 output
  float* emb  = outp + (size_t)N*8;

  const int Npad = ((N + 63)/64)*64;
  const int nbB  = (E + 4095)/4096;

  char* ws = (char*)d_ws;
  size_t o = 0;
  auto alloc = [&](size_t bytes)->char* {
    char* p = ws + o;
    o = (o + bytes + 255) & ~(size_t)255;
    return p;
  };
  int*      ghist = (int*)alloc(512*4);                            // [0:256) hist, [256:512) gcur
  int*      gcur  = ghist + 256;
  int*      dflag = (int*)alloc((size_t)nbB*4);
  int*      offs  = (int*)alloc((size_t)(N+1)*4);
  unsigned int* pairs = (unsigned int*)alloc((size_t)E*4);         // packed (dloc:9 | src:17)
  int*      csr   = (int*)alloc((size_t)E*4);
  ushort_t* wperm = (ushort_t*)alloc(74752ull*2);
  ushort_t* xb    = (ushort_t*)alloc(((size_t)Npad + 64)*64*2);    // bf16 x (+zero row N)
  ushort_t* hbuf  = (ushort_t*)alloc((size_t)Npad*128*2);          // gather output (row-major)
  ushort_t* x1    = (ushort_t*)alloc(((size_t)Npad + 64)*128*2);   // layer-1 output (+zero row N)
  ushort_t* ybuf  = (ushort_t*)alloc(((size_t)Npad + 64)*64*2);    // y3 = x2@W3a (+zero row N)

  hipMemsetAsync(ghist, 0, 512*4, stream);                         // hist + gcur
  const int tobfB = (N*32 + 1023)/1024;
  const int permB = (74752 + 256 + 1023)/1024;
  k_prep<<<nbB + tobfB + permB, 1024, 0, stream>>>(ew, ghist, dflag, E, N, nbB,
                                                   (const float2*)x, (unsigned int*)xb, N*32, tobfB,
                                                   W1a, W1b, W2a, W2b, W3a, W3b, Wfc, wperm,
                                                   xb + (size_t)N*64, x1 + (size_t)N*128, ybuf + (size_t)N*64);
  k_bin<<<nbB, 1024, 0, stream>>>(ew, ghist, dflag, gcur, pairs, E, N, NB);
  k_bcsr<<<NB, 1024, 0, stream>>>(pairs, ghist, offs, csr, N, NB);

  // layer 1 (64 -> 128): gather F=64 (2 nodes/wave) + MLP
  k_gatherx<64><<<(N+7)/8, 256, 0, stream>>>((const uint4*)xb, offs, csr, eps1,
                                             (uint4*)hbuf, N, N);
  k_mlp<64,128,128,false,false><<<Npad/64, 256, 0, stream>>>(hbuf, wperm+0, b1a, wperm+8192, b1b,
                                                             x1, nullptr, nullptr, nullptr, nullptr, N);
  // layer 2 (128 -> 128): row gather + MLP with y3 = x2@W3a pre-transform
  k_gatherx<128><<<(N+3)/4, 256, 0, stream>>>((const uint4*)x1, offs, csr, eps2,
                                              (uint4*)hbuf, N, N);
  k_mlp<128,128,128,false,true><<<Npad/64, 256, 0, stream>>>(hbuf, wperm+24576, b2a, wperm+40960, b2b,
                                                             ybuf, nullptr, wperm+57344, nullptr, nullptr, N);
  // layer 3: gather on y3 (F=64), then identity-GEMM1 (bias+relu) + W3b + FC
  k_gatherx<64><<<(N+7)/8, 256, 0, stream>>>((const uint4*)ybuf, offs, csr, eps3,
                                             (uint4*)hbuf, N, N);
  k_mlp<64,64,64,true,false><<<Npad/64, 256, 0, stream>>>(hbuf, wperm+70656, b3a, wperm+65536, b3b,
                                                          nullptr, emb, wperm+69632, bfc, outp, N);
}